// Round 2
// baseline (105.659 us; speedup 1.0000x reference)
//
#include <hip/hip_runtime.h>

#define C2 2.8853900817779268f  // 2*log2(e)
#define DIN 1024
#define HD 512

typedef short short8 __attribute__((ext_vector_type(8)));   // 8 bf16 (4 VGPRs)
typedef float floatx4 __attribute__((ext_vector_type(4)));  // MFMA acc

__device__ __forceinline__ float rcp_fast(float x){ return __builtin_amdgcn_rcpf(x); }
__device__ __forceinline__ float exp2_fast(float x){ return __builtin_amdgcn_exp2f(x); }
__device__ __forceinline__ unsigned short f2bf(float f){   // RNE fp32->bf16
    union{float f; unsigned int u;} v; v.f = f;
    unsigned int u = v.u;
    return (unsigned short)((u + 0x7FFFu + ((u >> 16) & 1u)) >> 16);
}

// ---------- convert: x, Wh, Wm (fp32) -> bf16; one block also computes c0 = b2 + sum(w2) ----------
__global__ __launch_bounds__(256) void convert_kernel(
    const float* __restrict__ x, const float* __restrict__ Wh,
    const float* __restrict__ Wm, const float* __restrict__ w2,
    const float* __restrict__ b2, unsigned short* __restrict__ xb,
    unsigned short* __restrict__ whb, unsigned short* __restrict__ wmb,
    float* __restrict__ c0out)
{
    int r = blockIdx.z;
    const float* s = r == 0 ? x : r == 1 ? Wh : Wm;
    unsigned short* d = r == 0 ? xb : r == 1 ? whb : wmb;
    int tid = threadIdx.x;
    int i = (blockIdx.x * 256 + tid) * 4;   // 512 blocks x 256 thr x 4 = 524288
    float4 v = *(const float4*)(s + i);
    ushort4 o = { f2bf(v.x), f2bf(v.y), f2bf(v.z), f2bf(v.w) };
    *(ushort4*)(d + i) = o;

    if (blockIdx.z == 2 && blockIdx.x == 0){   // c0 = b2 + sum(w2)  (block-uniform branch)
        __shared__ float red[2];
        float sum = 0.f;
        if (tid < 128){ float4 w = ((const float4*)w2)[tid]; sum = w.x + w.y + w.z + w.w; }
        #pragma unroll
        for (int off = 32; off; off >>= 1) sum += __shfl_down(sum, off, 64);
        if (tid < 128 && (tid & 63) == 0) red[tid >> 6] = sum;
        __syncthreads();
        if (tid == 0) c0out[0] = red[0] + red[1] + b2[0];
    }
}

// ---------- MFMA gemm + fused exp2 epilogue ----------
// C[s,j] = sum_k x[s,k] * W[j,k];  E[s][j] = exp2(C2*(C+bias[j]))  (both mats row-major)
// One 16x16 C tile per wave via mfma_f32_16x16x32_bf16, K=1024 in 32-steps.
// C/D: col=lane&15, row=quad*4+reg  [m89/m120-verified layouts]
__global__ __launch_bounds__(256) void mfma_gemm_kernel(
    const unsigned short* __restrict__ xb, const unsigned short* __restrict__ whb,
    const unsigned short* __restrict__ wmb, const float* __restrict__ bh,
    const float* __restrict__ bm, float* __restrict__ EH, float* __restrict__ EM)
{
    int mat = blockIdx.z;
    const unsigned short* B = mat ? wmb : whb;
    const float* bias = mat ? bm : bh;
    float* O = mat ? EM : EH;
    int j0 = blockIdx.x * 32, s0 = blockIdx.y * 32;
    int wave = threadIdx.x >> 6, lane = threadIdx.x & 63;
    int sw = (wave & 1) * 16, jw = (wave >> 1) * 16;
    int m = lane & 15, quad = lane >> 4;

    const unsigned short* ap = xb + (size_t)(s0 + sw + m) * DIN + quad * 8;
    const unsigned short* bp = B  + (size_t)(j0 + jw + m) * DIN + quad * 8;

    floatx4 acc = {0.f, 0.f, 0.f, 0.f};
    #pragma unroll 8
    for (int k = 0; k < DIN; k += 32){
        short8 af = *(const short8*)(ap + k);
        short8 bf = *(const short8*)(bp + k);
        acc = __builtin_amdgcn_mfma_f32_16x16x32_bf16(af, bf, acc, 0, 0, 0);
    }
    int col = j0 + jw + m;
    float bv = bias[col];
    #pragma unroll
    for (int i = 0; i < 4; i++){
        int row = s0 + sw + quad * 4 + i;
        O[(size_t)row * HD + col] = exp2_fast(C2 * (acc[i] + bv));
    }
}

// ---------- scores (direct): out[h,m] = c0 - 2 * sum_d w2[d] / (1 + EH[h,d]*EM[m,d])
// Grid 32x32 (16m x 16h tile per block), 256 thr, 1 output/thread, full d=512 loop
// in 8 chunks of 64, double-buffered LDS (T14: issue loads early, ds_write after compute).
// 4-term reciprocal pairing: one v_rcp per 4 d-elems.  w2 read via uniform (scalar) loads.
__global__ __launch_bounds__(256, 4) void scores_kernel(
    const float* __restrict__ EH, const float* __restrict__ EM,
    const float* __restrict__ w2, const float* __restrict__ c0p,
    float* __restrict__ out)
{
    int m0 = blockIdx.x * 16, h0 = blockIdx.y * 16;
    __shared__ float Hs[2][16 * 68];
    __shared__ float Ms[2][16 * 68];
    int tid = threadIdx.x;
    int tx = tid & 15, ty = tid >> 4;          // compute role: (h0+ty, m0+tx)
    // staging role: row ty (0..15), float4 slot tx (0..15)
    const float* hp = EH + (size_t)(h0 + ty) * HD + tx * 4;
    const float* mp = EM + (size_t)(m0 + ty) * HD + tx * 4;
    int ldst = ty * 68 + tx * 4;

    float4 hr = *(const float4*)hp;
    float4 mr = *(const float4*)mp;
    *(float4*)&Hs[0][ldst] = hr;
    *(float4*)&Ms[0][ldst] = mr;
    __syncthreads();

    float acc = 0.f;
    for (int c = 0; c < 7; ++c){
        // issue next chunk's global loads (latency hides under compute)
        hr = *(const float4*)(hp + (c + 1) * 64);
        mr = *(const float4*)(mp + (c + 1) * 64);
        const float* Hrow = &Hs[c & 1][ty * 68];
        const float* Mrow = &Ms[c & 1][tx * 68];
        const float* wc = w2 + c * 64;
        #pragma unroll
        for (int it = 0; it < 16; it++){
            int dk = it * 4;
            float4 hv = *(const float4*)(Hrow + dk);
            float4 mv = *(const float4*)(Mrow + dk);
            float w0 = wc[dk], w1 = wc[dk + 1], w2v = wc[dk + 2], w3 = wc[dk + 3];
            float den0 = fmaf(hv.x, mv.x, 1.f);
            float den1 = fmaf(hv.y, mv.y, 1.f);
            float den2 = fmaf(hv.z, mv.z, 1.f);
            float den3 = fmaf(hv.w, mv.w, 1.f);
            float p01 = den0 * den1, p23 = den2 * den3;
            float t1 = fmaf(w1, den0, w0 * den1);
            float t2 = fmaf(w3, den2, w2v * den3);
            float N  = fmaf(t2, p01, t1 * p23);
            acc = fmaf(N, rcp_fast(p01 * p23), acc);
        }
        // write next chunk into the other buffer (prev readers of it passed last barrier)
        *(float4*)&Hs[(c + 1) & 1][ldst] = hr;
        *(float4*)&Ms[(c + 1) & 1][ldst] = mr;
        __syncthreads();
    }
    {   // final chunk c=7 from buffer 1
        const float* Hrow = &Hs[1][ty * 68];
        const float* Mrow = &Ms[1][tx * 68];
        const float* wc = w2 + 7 * 64;
        #pragma unroll
        for (int it = 0; it < 16; it++){
            int dk = it * 4;
            float4 hv = *(const float4*)(Hrow + dk);
            float4 mv = *(const float4*)(Mrow + dk);
            float w0 = wc[dk], w1 = wc[dk + 1], w2v = wc[dk + 2], w3 = wc[dk + 3];
            float den0 = fmaf(hv.x, mv.x, 1.f);
            float den1 = fmaf(hv.y, mv.y, 1.f);
            float den2 = fmaf(hv.z, mv.z, 1.f);
            float den3 = fmaf(hv.w, mv.w, 1.f);
            float p01 = den0 * den1, p23 = den2 * den3;
            float t1 = fmaf(w1, den0, w0 * den1);
            float t2 = fmaf(w3, den2, w2v * den3);
            float N  = fmaf(t2, p01, t1 * p23);
            acc = fmaf(N, rcp_fast(p01 * p23), acc);
        }
    }
    float c0 = c0p[0];
    out[(size_t)(h0 + ty) * 512 + m0 + tx] = fmaf(-2.f, acc, c0);
}

extern "C" void kernel_launch(void* const* d_in, const int* in_sizes, int n_in,
                              void* d_out, int out_size, void* d_ws, size_t ws_size,
                              hipStream_t stream) {
    const float* x   = (const float*)d_in[0];   // [1,512,1024]
    const float* Wh  = (const float*)d_in[1];   // [512,1024]
    const float* bh  = (const float*)d_in[2];   // [512]
    const float* Wm  = (const float*)d_in[3];   // [512,1024]
    const float* bm  = (const float*)d_in[4];   // [512]
    const float* w2  = (const float*)d_in[5];   // [512]
    const float* b2  = (const float*)d_in[6];   // [1]
    float* out = (float*)d_out;                 // [512,512]
    (void)in_sizes; (void)n_in; (void)out_size; (void)ws_size;

    float* w = (float*)d_ws;
    unsigned short* xb  = (unsigned short*)(w);            // 524288 bf16 = 262144 f
    unsigned short* whb = (unsigned short*)(w + 262144);   // 262144 f
    unsigned short* wmb = (unsigned short*)(w + 524288);   // 262144 f
    float* EH = w + 786432;                                // 262144
    float* EM = w + 1048576;                               // 262144
    float* c0 = w + 1310720;                               // 1

    convert_kernel<<<dim3(512, 1, 3), 256, 0, stream>>>(x, Wh, Wm, w2, b2, xb, whb, wmb, c0);
    mfma_gemm_kernel<<<dim3(16, 16, 2), 256, 0, stream>>>(xb, whb, wmb, bh, bm, EH, EM);
    scores_kernel<<<dim3(32, 32), 256, 0, stream>>>(EH, EM, w2, c0, out);
}

// Round 4
// 104.758 us; speedup vs baseline: 1.0086x; 1.0086x over previous
//
#include <hip/hip_runtime.h>

#define C2 2.8853900817779268f  // 2*log2(e)
#define DIN 1024
#define HD 512

typedef short short8 __attribute__((ext_vector_type(8)));   // 8 bf16 (4 VGPRs)
typedef float floatx4 __attribute__((ext_vector_type(4)));  // MFMA acc
typedef float f32x2 __attribute__((ext_vector_type(2)));    // packed fp32 pair

__device__ __forceinline__ float rcp_fast(float x){ return __builtin_amdgcn_rcpf(x); }
__device__ __forceinline__ float exp2_fast(float x){ return __builtin_amdgcn_exp2f(x); }
__device__ __forceinline__ unsigned short f2bf(float f){   // RNE fp32->bf16
    union{float f; unsigned int u;} v; v.f = f;
    unsigned int u = v.u;
    return (unsigned short)((u + 0x7FFFu + ((u >> 16) & 1u)) >> 16);
}
// packed fp32 via compiler ISel (v_pk_fma_f32 / v_pk_mul_f32 on gfx90a+):
// vector ops guarantee correct regalloc/op_sel, unlike hand-written VOP3P asm.
__device__ __forceinline__ f32x2 pk_fma(f32x2 a, f32x2 b, f32x2 c){
    return __builtin_elementwise_fma(a, b, c);
}
__device__ __forceinline__ f32x2 pk_mul(f32x2 a, f32x2 b){ return a * b; }

// ---------- convert: x, Wh, Wm (fp32) -> bf16 buffers ----------
__global__ __launch_bounds__(256) void convert_kernel(
    const float* __restrict__ x, const float* __restrict__ Wh,
    const float* __restrict__ Wm, unsigned short* __restrict__ xb,
    unsigned short* __restrict__ whb, unsigned short* __restrict__ wmb)
{
    int r = blockIdx.z;
    const float* s = r == 0 ? x : r == 1 ? Wh : Wm;
    unsigned short* d = r == 0 ? xb : r == 1 ? whb : wmb;
    int i = (blockIdx.x * 256 + threadIdx.x) * 4;   // 512 blocks x 256 thr x 4 = 524288
    float4 v = *(const float4*)(s + i);
    ushort4 o = { f2bf(v.x), f2bf(v.y), f2bf(v.z), f2bf(v.w) };
    *(ushort4*)(d + i) = o;
}

// ---------- MFMA gemm + fused exp2 epilogue ----------
// C[s,j] = sum_k x[s,k] * W[j,k];  E = exp2(C2*(C+bias[j]))
// mat=0 -> EH[s][j] (row-major); mat=1 -> EMT[j][s] (transposed for scores staging)
// C/D: col=lane&15, row=quad*4+reg  [m89/m120-verified layouts]
__global__ __launch_bounds__(256) void mfma_gemm_kernel(
    const unsigned short* __restrict__ xb, const unsigned short* __restrict__ whb,
    const unsigned short* __restrict__ wmb, const float* __restrict__ bh,
    const float* __restrict__ bm, float* __restrict__ EH, float* __restrict__ EMT)
{
    int mat = blockIdx.z;
    const unsigned short* B = mat ? wmb : whb;
    const float* bias = mat ? bm : bh;
    int j0 = blockIdx.x * 32, s0 = blockIdx.y * 32;
    int wave = threadIdx.x >> 6, lane = threadIdx.x & 63;
    int sw = (wave & 1) * 16, jw = (wave >> 1) * 16;
    int m = lane & 15, quad = lane >> 4;

    const unsigned short* ap = xb + (size_t)(s0 + sw + m) * DIN + quad * 8;
    const unsigned short* bp = B  + (size_t)(j0 + jw + m) * DIN + quad * 8;

    floatx4 acc = {0.f, 0.f, 0.f, 0.f};
    #pragma unroll 8
    for (int k = 0; k < DIN; k += 32){
        short8 af = *(const short8*)(ap + k);
        short8 bf = *(const short8*)(bp + k);
        acc = __builtin_amdgcn_mfma_f32_16x16x32_bf16(af, bf, acc, 0, 0, 0);
    }
    int col = j0 + jw + m;
    float bv = bias[col];
    if (mat == 0){
        #pragma unroll
        for (int i = 0; i < 4; i++){
            int row = s0 + sw + quad * 4 + i;
            EH[(size_t)row * HD + col] = exp2_fast(C2 * (acc[i] + bv));
        }
    } else {
        // EMT[d=col][m-rows]: quads 0..3 of a given m-lane cover one 64B line
        float4 v = { exp2_fast(C2 * (acc[0] + bv)), exp2_fast(C2 * (acc[1] + bv)),
                     exp2_fast(C2 * (acc[2] + bv)), exp2_fast(C2 * (acc[3] + bv)) };
        *(float4*)&EMT[(size_t)col * 512 + s0 + sw + quad * 4] = v;
    }
}

// ---------- scores partial: Q[ds][h][m] = sum_{d in slice} (-2 w2[d]) * rcp(1+EH[h,d]*EM[m,d])
// 32h x 64m x 64d blocks (1024 blocks, 4/CU), 256 thr, 2x4 micro.
// Packed-fp32 dual groups: even d's in lo lane, odd d's in hi lane of f32x2.
// Per 8 d's per output: 14 pk-ops + 2 v_rcp (vs 30 scalar VALU slots).
// Hs [h][d] stride 68; Ms2 [dpair][m] float2-interleaved (even,odd), stride 132.
__global__ __launch_bounds__(256, 4) void scores_kernel(
    const float* __restrict__ EH, const float* __restrict__ EMT,
    const float* __restrict__ w2, float* __restrict__ Q)
{
    int m0 = blockIdx.x * 64, h0 = blockIdx.y * 32, d0 = blockIdx.z * 64;
    __shared__ float Hs[32 * 68];
    __shared__ float Ms2[32 * 132];   // [dp][m*2]: (EM[m][d0+2dp], EM[m][d0+2dp+1])
    __shared__ float wsS[64];
    int tid = threadIdx.x;
    int tx = tid & 15, ty = tid >> 4;   // tx: m-group (x4), ty: h-group (x2)
    #pragma unroll
    for (int l = 0; l < 2; l++){        // Hs: 32 rows x 16 float4
        int slot = tid + 256 * l;
        int row = slot >> 4, q = slot & 15;
        *(float4*)&Hs[row * 68 + q * 4] =
            *(const float4*)(EH + (size_t)(h0 + row) * HD + d0 + q * 4);
    }
    #pragma unroll
    for (int l = 0; l < 2; l++){        // Ms2: 32 dpairs x 16 m-quads, interleave 2 EMT rows
        int slot = tid + 256 * l;
        int dp = slot >> 4, mq = slot & 15;
        float4 r0 = *(const float4*)(EMT + (size_t)(d0 + 2*dp    ) * 512 + m0 + mq * 4);
        float4 r1 = *(const float4*)(EMT + (size_t)(d0 + 2*dp + 1) * 512 + m0 + mq * 4);
        float* base = &Ms2[dp * 132 + mq * 8];
        float4 w0 = { r0.x, r1.x, r0.y, r1.y };
        float4 w1 = { r0.z, r1.z, r0.w, r1.w };
        *(float4*)(base)     = w0;
        *(float4*)(base + 4) = w1;
    }
    if (tid < 16){
        float4 w = *(const float4*)(w2 + d0 + tid * 4);
        float4 ws = {-2.f * w.x, -2.f * w.y, -2.f * w.z, -2.f * w.w};
        *(float4*)&wsS[tid * 4] = ws;
    }
    __syncthreads();

    f32x2 acc2[2][4] = {};
    const f32x2 one2 = {1.f, 1.f};
    int hrow0 = ty * 2;
    #pragma unroll 1
    for (int it = 0; it < 8; it++){
        int dk = it * 8;
        float4 wa = *(const float4*)&wsS[dk];
        float4 wb = *(const float4*)&wsS[dk + 4];
        f32x2 wP0 = {wa.x, wa.y}, wP1 = {wa.z, wa.w};
        f32x2 wP2 = {wb.x, wb.y}, wP3 = {wb.z, wb.w};
        f32x2 hP[2][4];
        #pragma unroll
        for (int i = 0; i < 2; i++){
            float4 a0 = *(const float4*)&Hs[(hrow0 + i) * 68 + dk];
            float4 a1 = *(const float4*)&Hs[(hrow0 + i) * 68 + dk + 4];
            hP[i][0] = {a0.x, a0.y}; hP[i][1] = {a0.z, a0.w};
            hP[i][2] = {a1.x, a1.y}; hP[i][3] = {a1.z, a1.w};
        }
        #pragma unroll
        for (int jp = 0; jp < 2; jp++){          // output m's {2jp, 2jp+1}
            f32x2 mP[4][2];
            #pragma unroll
            for (int p = 0; p < 4; p++){
                int dp = dk / 2 + p;
                float4 q = *(const float4*)&Ms2[dp * 132 + tx * 8 + jp * 4];
                mP[p][0] = {q.x, q.y}; mP[p][1] = {q.z, q.w};
            }
            #pragma unroll
            for (int i = 0; i < 2; i++){
                #pragma unroll
                for (int jj = 0; jj < 2; jj++){
                    f32x2 den0 = pk_fma(hP[i][0], mP[0][jj], one2);
                    f32x2 den1 = pk_fma(hP[i][1], mP[1][jj], one2);
                    f32x2 den2 = pk_fma(hP[i][2], mP[2][jj], one2);
                    f32x2 den3 = pk_fma(hP[i][3], mP[3][jj], one2);
                    f32x2 p01 = pk_mul(den0, den1);
                    f32x2 p23 = pk_mul(den2, den3);
                    f32x2 t1 = pk_fma(wP1, den0, pk_mul(wP0, den1));
                    f32x2 t2 = pk_fma(wP3, den2, pk_mul(wP2, den3));
                    f32x2 N  = pk_fma(t2, p01, pk_mul(t1, p23));
                    f32x2 D  = pk_mul(p01, p23);
                    f32x2 r  = { rcp_fast(D.x), rcp_fast(D.y) };
                    acc2[i][jp * 2 + jj] = pk_fma(N, r, acc2[i][jp * 2 + jj]);
                }
            }
        }
    }
    float* Qp = Q + (size_t)blockIdx.z * 262144;
    #pragma unroll
    for (int i = 0; i < 2; i++){
        float4 v = { acc2[i][0].x + acc2[i][0].y, acc2[i][1].x + acc2[i][1].y,
                     acc2[i][2].x + acc2[i][2].y, acc2[i][3].x + acc2[i][3].y };
        *(float4*)&Qp[(h0 + ty * 2 + i) * 512 + m0 + tx * 4] = v;
    }
}

// ---------- combine: out = c0 + sum of 8 d-slice partials, c0 = b2 + sum(w2)
__global__ __launch_bounds__(256) void combine_kernel(
    const float* __restrict__ Q, const float* __restrict__ w2,
    const float* __restrict__ b2, float* __restrict__ out)
{
    int tid = threadIdx.x;
    __shared__ float red[4];
    __shared__ float c0s;
    float s = 0.f;
    if (tid < 128){ float4 v = ((const float4*)w2)[tid]; s = v.x + v.y + v.z + v.w; }
    #pragma unroll
    for (int off = 32; off; off >>= 1) s += __shfl_down(s, off, 64);
    if (tid < 128 && (tid & 63) == 0) red[tid >> 6] = s;
    __syncthreads();
    if (tid == 0) c0s = red[0] + red[1] + b2[0];
    __syncthreads();
    float c0 = c0s;
    int g = blockIdx.x * 256 + tid;
    const float4* Q4 = (const float4*)Q;
    float4 a = Q4[g];
    #pragma unroll
    for (int sl = 1; sl < 8; sl++){
        float4 b = Q4[sl * 65536 + g];
        a.x += b.x; a.y += b.y; a.z += b.z; a.w += b.w;
    }
    float4 o = {a.x + c0, a.y + c0, a.z + c0, a.w + c0};
    ((float4*)out)[g] = o;
}

extern "C" void kernel_launch(void* const* d_in, const int* in_sizes, int n_in,
                              void* d_out, int out_size, void* d_ws, size_t ws_size,
                              hipStream_t stream) {
    const float* x   = (const float*)d_in[0];   // [1,512,1024]
    const float* Wh  = (const float*)d_in[1];   // [512,1024]
    const float* bh  = (const float*)d_in[2];   // [512]
    const float* Wm  = (const float*)d_in[3];   // [512,1024]
    const float* bm  = (const float*)d_in[4];   // [512]
    const float* w2  = (const float*)d_in[5];   // [512]
    const float* b2  = (const float*)d_in[6];   // [1]
    float* out = (float*)d_out;                 // [512,512]
    (void)in_sizes; (void)n_in; (void)out_size; (void)ws_size;

    float* w = (float*)d_ws;
    unsigned short* xb  = (unsigned short*)(w);            // 524288 bf16 = 262144 f
    unsigned short* whb = (unsigned short*)(w + 262144);   // 262144 f
    unsigned short* wmb = (unsigned short*)(w + 524288);   // 262144 f
    float* EH  = w + 786432;                               // 262144
    float* EMT = w + 1048576;                              // 262144 (transposed [d][m])
    float* Q   = w + 1310720;                              // 8 * 262144

    convert_kernel<<<dim3(512, 1, 3), 256, 0, stream>>>(x, Wh, Wm, xb, whb, wmb);
    mfma_gemm_kernel<<<dim3(16, 16, 2), 256, 0, stream>>>(xb, whb, wmb, bh, bm, EH, EMT);
    scores_kernel<<<dim3(8, 16, 8), 256, 0, stream>>>(EH, EMT, w2, Q);
    combine_kernel<<<256, 256, 0, stream>>>(Q, w2, b2, out);
}